// Round 12
// baseline (213.723 us; speedup 1.0000x reference)
//
#include <hip/hip_runtime.h>

typedef __bf16 bf16x8 __attribute__((ext_vector_type(8)));
typedef float  f32x4  __attribute__((ext_vector_type(4)));
typedef unsigned short ushortx8 __attribute__((ext_vector_type(8)));
typedef unsigned short ushortx4 __attribute__((ext_vector_type(4)));

static __device__ __forceinline__ unsigned short f2bf(float f) {
  unsigned int u = __builtin_bit_cast(unsigned int, f);
  u += 0x7FFFu + ((u >> 16) & 1u);
  return (unsigned short)(u >> 16);
}
static __device__ __forceinline__ unsigned short f2bf_fast(float f) {  // round-half-up
  unsigned int u = __builtin_bit_cast(unsigned int, f);
  return (unsigned short)((u + 0x8000u) >> 16);
}

#define GLL16(gp, lp) __builtin_amdgcn_global_load_lds(                       \
    (const __attribute__((address_space(1))) void*)(gp),                      \
    (__attribute__((address_space(3))) void*)(lp), 16, 0, 0)

// ---------------- prep: z<4 -> transpose+cast W (R10-proven); z>=4 -> cast X ----------------
__global__ __launch_bounds__(256) void prep_kernel(const float* __restrict__ X,
                                                   const float* __restrict__ W0,
                                                   const float* __restrict__ W1,
                                                   const float* __restrict__ W2,
                                                   const float* __restrict__ W3,
                                                   unsigned short* __restrict__ Xbf,
                                                   unsigned short* __restrict__ D0,
                                                   unsigned short* __restrict__ D1,
                                                   unsigned short* __restrict__ D2,
                                                   unsigned short* __restrict__ D3) {
  int z = blockIdx.z;
  if (z >= 4) {  // cast 4096x1024 fp32 -> bf16; z in {4,5}
    long bid = (long)(z - 4) * 1024 + blockIdx.y * 32 + blockIdx.x;
    int tl = threadIdx.y * 32 + threadIdx.x;
    long i = bid * 2048 + (long)tl * 8;
    float4 f0 = *(const float4*)(X + i);
    float4 f1 = *(const float4*)(X + i + 4);
    ushortx8 u;
    u[0] = f2bf(f0.x); u[1] = f2bf(f0.y); u[2] = f2bf(f0.z); u[3] = f2bf(f0.w);
    u[4] = f2bf(f1.x); u[5] = f2bf(f1.y); u[6] = f2bf(f1.z); u[7] = f2bf(f1.w);
    *(ushortx8*)(Xbf + i) = u;
    return;
  }
  const float* src = (z == 0) ? W0 : (z == 1) ? W1 : (z == 2) ? W2 : W3;
  unsigned short* dst = (z == 0) ? D0 : (z == 1) ? D1 : (z == 2) ? D2 : D3;
  const int R = 1024, C = 1024;
  __shared__ unsigned short t[32][33];
  int c = blockIdx.x * 32 + threadIdx.x;
#pragma unroll
  for (int i = 0; i < 4; ++i) {
    int r = blockIdx.y * 32 + threadIdx.y + i * 8;
    t[threadIdx.y + i * 8][threadIdx.x] = f2bf(src[(size_t)r * C + c]);
  }
  __syncthreads();
  int rr = blockIdx.y * 32 + threadIdx.x;
#pragma unroll
  for (int i = 0; i < 4; ++i) {
    int cc = blockIdx.x * 32 + threadIdx.y + i * 8;
    dst[(size_t)cc * R + rr] = t[threadIdx.x][threadIdx.y + i * 8];
  }
}

// ---------------- QKV GEMM: 128x128 tile, BK=32, static-dbuf async prefetch ----
// LDS slot (row, s) holds global chunk s ^ ((row>>1)&3)  [64B rows: even/odd bank halves]
__global__ __launch_bounds__(256) void gemm128_kernel(
    const unsigned short* __restrict__ A,
    const unsigned short* __restrict__ BT0,
    const unsigned short* __restrict__ BT1,
    const unsigned short* __restrict__ BT2,
    unsigned short* __restrict__ outQ,
    unsigned short* __restrict__ outK,
    unsigned short* __restrict__ outVT,
    const int* __restrict__ pos_ids,
    const float* __restrict__ cosb,
    const float* __restrict__ sinb) {
  const int K = 1024;
  int id = blockIdx.x + 8 * (blockIdx.y + 32 * blockIdx.z);
  int m_idx = id & 31;         // m fastest => xcd = id%8 = m_idx%8
  int nzi = id >> 5;
  int n_idx = nzi & 7;
  int z = nzi >> 3;
  const unsigned short* BT = (z == 0) ? BT0 : (z == 1 ? BT1 : BT2);
  int n0 = n_idx * 128, m0 = m_idx * 128;
  int t = threadIdx.x, lane = t & 63, w = t >> 6;
  int wy = w >> 1, wx = w & 1;
  int n16 = lane & 15, quad = lane >> 4;
  __shared__ __align__(16) unsigned short sA0[128 * 32];
  __shared__ __align__(16) unsigned short sA1[128 * 32];
  __shared__ __align__(16) unsigned short sB0[128 * 32];
  __shared__ __align__(16) unsigned short sB1[128 * 32];

  int r4 = lane >> 2, c4 = lane & 3;
  int fs = c4 ^ ((r4 >> 1) & 3);  // fetch chunk for slot c4, rows r4 and r4+16
  const char* gA = (const char*)(A + (size_t)(m0 + w * 32 + r4) * K) + fs * 16;
  const char* gB = (const char*)(BT + (size_t)(n0 + w * 32 + r4) * K) + fs * 16;
  const size_t row16 = (size_t)16 * K * 2;

  f32x4 acc[4][4];
#pragma unroll
  for (int i = 0; i < 4; ++i)
#pragma unroll
    for (int j = 0; j < 4; ++j) acc[i][j] = f32x4{0.f, 0.f, 0.f, 0.f};

#define GSTAGE(kk_, SA, SB)                                                     \
  do {                                                                          \
    GLL16(gA + (size_t)(kk_) * 2, SA + (w * 32) * 32);                          \
    GLL16(gA + (size_t)(kk_) * 2 + row16, SA + (w * 32 + 16) * 32);             \
    GLL16(gB + (size_t)(kk_) * 2, SB + (w * 32) * 32);                          \
    GLL16(gB + (size_t)(kk_) * 2 + row16, SB + (w * 32 + 16) * 32);             \
  } while (0)

#define GCOMPUTE(SA, SB)                                                        \
  do {                                                                          \
    bf16x8 a[4], b[4];                                                          \
    int cs = (quad ^ ((n16 >> 1) & 3)) * 8;                                     \
    _Pragma("unroll") for (int i = 0; i < 4; ++i) {                             \
      a[i] = *(const bf16x8*)(&SA[(wy * 64 + i * 16 + n16) * 32 + cs]);         \
      b[i] = *(const bf16x8*)(&SB[(wx * 64 + i * 16 + n16) * 32 + cs]);         \
    }                                                                           \
    _Pragma("unroll") for (int mt = 0; mt < 4; ++mt)                            \
      _Pragma("unroll") for (int nt = 0; nt < 4; ++nt)                          \
        acc[mt][nt] = __builtin_amdgcn_mfma_f32_16x16x32_bf16(                  \
            a[mt], b[nt], acc[mt][nt], 0, 0, 0);                                \
  } while (0)

  GSTAGE(0, sA0, sB0);
  for (int kk = 0; kk < K;) {
    __syncthreads();
    if (kk + 32 < K) GSTAGE(kk + 32, sA1, sB1);
    GCOMPUTE(sA0, sB0);
    kk += 32;
    if (kk >= K) break;
    __syncthreads();
    if (kk + 32 < K) GSTAGE(kk + 32, sA0, sB0);
    GCOMPUTE(sA1, sB1);
    kk += 32;
  }
#undef GSTAGE
#undef GCOMPUTE

  if (z < 2) {  // fused RoPE on Q/K; Q additionally pre-scaled by SCALE*log2(e)
    const float qs = (z == 0) ? (0.125f * 1.44269504088896340736f) : 1.0f;
#pragma unroll
    for (int mt = 0; mt < 4; ++mt)
#pragma unroll
      for (int r = 0; r < 4; ++r) {
        int row = m0 + wy * 64 + mt * 16 + quad * 4 + r;
        int b = row >> 11, s = row & 2047;
        int pos = pos_ids[b * 2048 + s];
        const float* cb = cosb + (size_t)pos * 64;
        const float* sb = sinb + (size_t)pos * 64;
#pragma unroll
        for (int nt = 0; nt < 2; ++nt) {
          int d0 = nt * 16 + n16;
          float c0 = cb[d0] * qs, s0 = sb[d0] * qs;
          float c1 = cb[d0 + 32] * qs, s1 = sb[d0 + 32] * qs;
          float x0 = acc[mt][nt][r], x1 = acc[mt][nt + 2][r];
          acc[mt][nt][r]     = x0 * c0 - x1 * s0;
          acc[mt][nt + 2][r] = x1 * c1 + x0 * s1;
        }
      }
  }

  if (z == 2) {
    // V^T fused write: VT[((b*16+h)*64+d)*2048 + s]
#pragma unroll
    for (int mt = 0; mt < 4; ++mt)
#pragma unroll
      for (int nt = 0; nt < 4; ++nt) {
        int row = m0 + wy * 64 + mt * 16 + quad * 4;
        int b = row >> 11, s = row & 2047;
        int col = n0 + wx * 64 + nt * 16 + n16;
        int h = col >> 6, d = col & 63;
        ushortx4 u;
#pragma unroll
        for (int r = 0; r < 4; ++r) u[r] = f2bf(acc[mt][nt][r]);
        *(ushortx4*)(&outVT[(((size_t)b * 16 + h) * 64 + d) * 2048 + s]) = u;
      }
    return;
  }

#pragma unroll
  for (int mt = 0; mt < 4; ++mt)
#pragma unroll
    for (int nt = 0; nt < 4; ++nt)
#pragma unroll
      for (int r = 0; r < 4; ++r) {
        int row = m0 + wy * 64 + mt * 16 + quad * 4 + r;
        int col = n0 + wx * 64 + nt * 16 + n16;
        unsigned short* dst = (z == 0) ? outQ : outK;
        int b = row >> 11, s = row & 2047, h = col >> 6, d = col & 63;
        dst[(((size_t)b * 16 + h) * 2048 + s) * 64 + d] = f2bf(acc[mt][nt][r]);
      }
}

// ---------------- Wo GEMM: 64x64 tile -> 1024 blocks (4/CU), BK=32 static-dbuf ----
__global__ __launch_bounds__(256) void gemm64_kernel(const unsigned short* __restrict__ A,
                                                     const unsigned short* __restrict__ BT,
                                                     float* __restrict__ outF) {
  const int K = 1024, N = 1024;
  int m0 = blockIdx.x * 64, n0 = blockIdx.y * 64;
  int t = threadIdx.x, lane = t & 63, w = t >> 6;
  int wy = w >> 1, wx = w & 1;
  int n16 = lane & 15, quad = lane >> 4;
  __shared__ __align__(16) unsigned short sA0[64 * 32];
  __shared__ __align__(16) unsigned short sA1[64 * 32];
  __shared__ __align__(16) unsigned short sB0[64 * 32];
  __shared__ __align__(16) unsigned short sB1[64 * 32];

  int r4 = lane >> 2, c4 = lane & 3;
  int fs = c4 ^ ((r4 >> 1) & 3);
  const char* gA = (const char*)(A + (size_t)(m0 + w * 16 + r4) * K) + fs * 16;
  const char* gB = (const char*)(BT + (size_t)(n0 + w * 16 + r4) * K) + fs * 16;

  f32x4 acc[2][2];
#pragma unroll
  for (int i = 0; i < 2; ++i)
#pragma unroll
    for (int j = 0; j < 2; ++j) acc[i][j] = f32x4{0.f, 0.f, 0.f, 0.f};

#define WSTAGE(kk_, SA, SB)                                                     \
  do {                                                                          \
    GLL16(gA + (size_t)(kk_) * 2, SA + (w * 16) * 32);                          \
    GLL16(gB + (size_t)(kk_) * 2, SB + (w * 16) * 32);                          \
  } while (0)

#define WCOMPUTE(SA, SB)                                                        \
  do {                                                                          \
    int cs = (quad ^ ((n16 >> 1) & 3)) * 8;                                     \
    bf16x8 a0 = *(const bf16x8*)(&SA[(wy * 32 + n16) * 32 + cs]);               \
    bf16x8 a1 = *(const bf16x8*)(&SA[(wy * 32 + 16 + n16) * 32 + cs]);          \
    bf16x8 b0 = *(const bf16x8*)(&SB[(wx * 32 + n16) * 32 + cs]);               \
    bf16x8 b1 = *(const bf16x8*)(&SB[(wx * 32 + 16 + n16) * 32 + cs]);          \
    acc[0][0] = __builtin_amdgcn_mfma_f32_16x16x32_bf16(a0, b0, acc[0][0], 0, 0, 0); \
    acc[0][1] = __builtin_amdgcn_mfma_f32_16x16x32_bf16(a0, b1, acc[0][1], 0, 0, 0); \
    acc[1][0] = __builtin_amdgcn_mfma_f32_16x16x32_bf16(a1, b0, acc[1][0], 0, 0, 0); \
    acc[1][1] = __builtin_amdgcn_mfma_f32_16x16x32_bf16(a1, b1, acc[1][1], 0, 0, 0); \
  } while (0)

  WSTAGE(0, sA0, sB0);
  for (int kk = 0; kk < K;) {
    __syncthreads();
    if (kk + 32 < K) WSTAGE(kk + 32, sA1, sB1);
    WCOMPUTE(sA0, sB0);
    kk += 32;
    if (kk >= K) break;
    __syncthreads();
    if (kk + 32 < K) WSTAGE(kk + 32, sA0, sB0);
    WCOMPUTE(sA1, sB1);
    kk += 32;
  }
#undef WSTAGE
#undef WCOMPUTE

#pragma unroll
  for (int mt = 0; mt < 2; ++mt)
#pragma unroll
    for (int nt = 0; nt < 2; ++nt)
#pragma unroll
      for (int r = 0; r < 4; ++r) {
        int row = m0 + wy * 32 + mt * 16 + quad * 4 + r;
        int col = n0 + wx * 32 + nt * 16 + n16;
        outF[(size_t)row * N + col] = acc[mt][nt][r];
      }
}

// ---------------- Flash attention v8: q-tile 128, K-tile 128, 8 waves, dbuf ----
// S^T orientation; lane owns q-row qg. One softmax round + one barrier per 128 k-cols.
// PV done in two 64-k halves so sP stays 16x64/wave (80 KB total LDS -> 2 blk/CU).
__global__ __launch_bounds__(512, 4) void attn_kernel(const unsigned short* __restrict__ Q,
                                                      const unsigned short* __restrict__ Kk,
                                                      const unsigned short* __restrict__ VT,
                                                      unsigned short* __restrict__ O) {
  int bh = blockIdx.x;
  int qt = (int)(gridDim.y - 1 - blockIdx.y);  // 0..15, LPT
  int t = threadIdx.x;
  int lane = t & 63;
  int w = t >> 6;  // 0..7
  int n16 = lane & 15, quad = lane >> 4;
  int r8 = lane >> 3, c8 = lane & 7;   // K staging coords
  int rv = lane >> 4, cv = lane & 15;  // V staging coords
  const unsigned short* Qb = Q + (size_t)bh * 2048 * 64;
  const unsigned short* Kb = Kk + (size_t)bh * 2048 * 64;
  const unsigned short* Vb = VT + (size_t)bh * 64 * 2048;

  __shared__ __align__(16) unsigned short sK0[128 * 64];
  __shared__ __align__(16) unsigned short sK1[128 * 64];
  __shared__ __align__(16) unsigned short sV0[64 * 128];
  __shared__ __align__(16) unsigned short sV1[64 * 128];
  __shared__ __align__(16) unsigned short sP[8][16 * 64];
  unsigned short* spW = sP[w];

  int b_ = bh >> 4, h_ = bh & 15;
  int nk = qt + 1;
  int qg = qt * 128 + w * 16 + n16;  // this lane's q-row

  bf16x8 aQ[2];
#pragma unroll
  for (int kb = 0; kb < 2; ++kb)
    aQ[kb] = *(const bf16x8*)(Qb + (size_t)qg * 64 + kb * 32 + quad * 8);

  f32x4 o[4];
  float mst = -3e38f, lst = 0.f;
#pragma unroll
  for (int ct = 0; ct < 4; ++ct) o[ct] = f32x4{0.f, 0.f, 0.f, 0.f};

#define ASTAGE(kt_, SK, SV)                                                               \
  do {                                                                                    \
    const unsigned short* kg_ = Kb + (size_t)((kt_) * 128 + w * 16) * 64;                 \
    const unsigned short* vg_ = Vb + (size_t)(w * 8) * 2048 + (kt_) * 128;                \
    GLL16(kg_ + (size_t)r8 * 64 + (c8 ^ r8) * 8, SK + (w * 16) * 64);                     \
    GLL16(kg_ + (size_t)(8 + r8) * 64 + (c8 ^ r8) * 8, SK + (w * 16 + 8) * 64);           \
    GLL16(vg_ + (size_t)rv * 2048 + (cv ^ rv) * 8, SV + (w * 8) * 128);                   \
    GLL16(vg_ + (size_t)(4 + rv) * 2048 + (cv ^ (4 + rv)) * 8, SV + (w * 8 + 4) * 128);   \
  } while (0)

#define ACOMPUTE(kt_, SK, SV)                                                             \
  do {                                                                                    \
    f32x4 ps[2][4]; /* S^T: D[m=k][n=q]; 2 halves x 4 mt */                               \
    _Pragma("unroll") for (int h = 0; h < 2; ++h)                                         \
      _Pragma("unroll") for (int mt = 0; mt < 4; ++mt) {                                  \
        const unsigned short* kr = &SK[(h * 64 + mt * 16 + n16) * 64];                    \
        bf16x8 ka0 = *(const bf16x8*)(kr + ((quad ^ (n16 & 7)) * 8));                     \
        bf16x8 ka1 = *(const bf16x8*)(kr + (((4 + quad) ^ (n16 & 7)) * 8));               \
        f32x4 zv = f32x4{0.f, 0.f, 0.f, 0.f};                                             \
        zv = __builtin_amdgcn_mfma_f32_16x16x32_bf16(ka0, aQ[0], zv, 0, 0, 0);            \
        ps[h][mt] = __builtin_amdgcn_mfma_f32_16x16x32_bf16(ka1, aQ[1], zv, 0, 0, 0);     \
      }                                                                                   \
    if ((kt_) == nk - 1) { /* diagonal: mask k > q */                                     \
      _Pragma("unroll") for (int h = 0; h < 2; ++h)                                       \
        _Pragma("unroll") for (int mt = 0; mt < 4; ++mt)                                  \
          _Pragma("unroll") for (int r = 0; r < 4; ++r)                                   \
            if ((kt_) * 128 + h * 64 + mt * 16 + quad * 4 + r > qg) ps[h][mt][r] = -3e38f;\
    }                                                                                     \
    float rm = ps[0][0][0];                                                               \
    _Pragma("unroll") for (int h = 0; h < 2; ++h)                                         \
      _Pragma("unroll") for (int mt = 0; mt < 4; ++mt)                                    \
        _Pragma("unroll") for (int r = 0; r < 4; ++r) rm = fmaxf(rm, ps[h][mt][r]);       \
    rm = fmaxf(rm, __shfl_xor(rm, 16));                                                   \
    rm = fmaxf(rm, __shfl_xor(rm, 32));                                                   \
    float mn = fmaxf(mst, rm);                                                            \
    float al = exp2f(mst - mn);                                                           \
    mst = mn;                                                                             \
    float rs = 0.f;                                                                       \
    _Pragma("unroll") for (int h = 0; h < 2; ++h)                                         \
      _Pragma("unroll") for (int mt = 0; mt < 4; ++mt)                                    \
        _Pragma("unroll") for (int r = 0; r < 4; ++r) {                                   \
          ps[h][mt][r] = exp2f(ps[h][mt][r] - mn);                                        \
          rs += ps[h][mt][r];                                                             \
        }                                                                                 \
    lst = lst * al + rs;                                                                  \
    _Pragma("unroll") for (int ct = 0; ct < 4; ++ct)                                      \
      _Pragma("unroll") for (int r = 0; r < 4; ++r) o[ct][r] *= al;                       \
    _Pragma("unroll") for (int h = 0; h < 2; ++h) {                                       \
      _Pragma("unroll") for (int mt = 0; mt < 4; ++mt) {                                  \
        ushortx4 uu;                                                                      \
        _Pragma("unroll") for (int r = 0; r < 4; ++r) uu[r] = f2bf_fast(ps[h][mt][r]);    \
        int ch = (2 * mt + (quad >> 1)) ^ (n16 & 7);                                      \
        *(ushortx4*)(&spW[n16 * 64 + ch * 8 + (quad & 1) * 4]) = uu;                      \
      }                                                                                   \
      __builtin_amdgcn_s_waitcnt(0xC07F); /* lgkmcnt(0); GLL prefetch stays in flight */  \
      bf16x8 aP0 = *(const bf16x8*)(&spW[n16 * 64 + ((quad ^ (n16 & 7)) * 8)]);           \
      bf16x8 aP1 = *(const bf16x8*)(&spW[n16 * 64 + (((4 + quad) ^ (n16 & 7)) * 8)]);     \
      _Pragma("unroll") for (int ct = 0; ct < 4; ++ct) {                                  \
        const unsigned short* vr = &SV[(ct * 16 + n16) * 128];                            \
        bf16x8 va0 = *(const bf16x8*)(vr + ((((h * 2 + 0) * 4 + quad) ^ (n16 & 7)) * 8)); \
        bf16x8 va1 = *(const bf16x8*)(vr + ((((h * 2 + 1) * 4 + quad) ^ (n16 & 7)) * 8)); \
        o[ct] = __builtin_amdgcn_mfma_f32_16x16x32_bf16(va0, aP0, o[ct], 0, 0, 0);        \
        o[ct] = __builtin_amdgcn_mfma_f32_16x16x32_bf16(va1, aP1, o[ct], 0, 0, 0);        \
      }                                                                                   \
    }                                                                                     \
  } while (0)

  ASTAGE(0, sK0, sV0);
  int kt = 0;
  while (true) {
    __syncthreads();  // drains loads into sK0/sV0
    if (kt + 1 < nk) ASTAGE(kt + 1, sK1, sV1);
    ACOMPUTE(kt, sK0, sV0);
    if (++kt == nk) break;
    __syncthreads();  // drains loads into sK1/sV1
    if (kt + 1 < nk) ASTAGE(kt + 1, sK0, sV0);
    ACOMPUTE(kt, sK1, sV1);
    if (++kt == nk) break;
  }
#undef ASTAGE
#undef ACOMPUTE

  // cross-quad l reduction (quads hold disjoint k-partials)
  lst += __shfl_xor(lst, 16);
  lst += __shfl_xor(lst, 32);
  float inv = 1.0f / lst;

#pragma unroll
  for (int ct = 0; ct < 4; ++ct) {
    ushortx4 uo;
#pragma unroll
    for (int r = 0; r < 4; ++r) uo[r] = f2bf(o[ct][r] * inv);
    size_t addr = ((size_t)b_ * 2048 + qg) * 1024 + h_ * 64 + ct * 16 + quad * 4;
    *(ushortx4*)(&O[addr]) = uo;
  }
}

// ---------------- launch ----------------
extern "C" void kernel_launch(void* const* d_in, const int* in_sizes, int n_in,
                              void* d_out, int out_size, void* d_ws, size_t ws_size,
                              hipStream_t stream) {
  const float* X    = (const float*)d_in[0];
  const int*   pos  = (const int*)d_in[2];
  const float* cosb = (const float*)d_in[3];
  const float* sinb = (const float*)d_in[4];
  const float* Wq   = (const float*)d_in[5];
  const float* Wk   = (const float*)d_in[6];
  const float* Wv   = (const float*)d_in[7];
  const float* Wo   = (const float*)d_in[8];
  float* out = (float*)d_out;

  char* ws = (char*)d_ws;
  const size_t SZ_X = 4096UL * 1024 * 2;
  const size_t SZ_W = 1024UL * 1024 * 2;
  unsigned short* Xbf = (unsigned short*)(ws);
  unsigned short* WTq = (unsigned short*)(ws + SZ_X);
  unsigned short* WTk = (unsigned short*)(ws + SZ_X + SZ_W);
  unsigned short* WTv = (unsigned short*)(ws + SZ_X + 2 * SZ_W);
  unsigned short* WTo = (unsigned short*)(ws + SZ_X + 3 * SZ_W);
  unsigned short* Qbf = (unsigned short*)(ws + SZ_X + 4 * SZ_W);
  unsigned short* Kbf = (unsigned short*)(ws + 2 * SZ_X + 4 * SZ_W);
  unsigned short* VTr = (unsigned short*)(ws + 3 * SZ_X + 4 * SZ_W);
  unsigned short* Obf = (unsigned short*)(ws + 4 * SZ_X + 4 * SZ_W);

  prep_kernel<<<dim3(32, 32, 6), dim3(32, 8), 0, stream>>>(
      X, Wq, Wk, Wv, Wo, Xbf, WTq, WTk, WTv, WTo);

  // QKV projections + fused RoPE (Q pre-scaled) + fused V-transpose
  gemm128_kernel<<<dim3(8, 32, 3), 256, 0, stream>>>(Xbf, WTq, WTk, WTv,
                                                     Qbf, Kbf, VTr,
                                                     pos, cosb, sinb);

  attn_kernel<<<dim3(32, 16), 512, 0, stream>>>(Qbf, Kbf, VTr, Obf);

  gemm64_kernel<<<dim3(64, 16), 256, 0, stream>>>(Obf, WTo, out);
}

// Round 13
// 213.440 us; speedup vs baseline: 1.0013x; 1.0013x over previous
//
#include <hip/hip_runtime.h>

typedef __bf16 bf16x8 __attribute__((ext_vector_type(8)));
typedef float  f32x4  __attribute__((ext_vector_type(4)));
typedef unsigned short ushortx8 __attribute__((ext_vector_type(8)));
typedef unsigned short ushortx4 __attribute__((ext_vector_type(4)));

static __device__ __forceinline__ unsigned short f2bf(float f) {
  unsigned int u = __builtin_bit_cast(unsigned int, f);
  u += 0x7FFFu + ((u >> 16) & 1u);
  return (unsigned short)(u >> 16);
}
static __device__ __forceinline__ unsigned short f2bf_fast(float f) {  // round-half-up
  unsigned int u = __builtin_bit_cast(unsigned int, f);
  return (unsigned short)((u + 0x8000u) >> 16);
}

#define GLL16(gp, lp) __builtin_amdgcn_global_load_lds(                       \
    (const __attribute__((address_space(1))) void*)(gp),                      \
    (__attribute__((address_space(3))) void*)(lp), 16, 0, 0)

// ---------------- prep: z<4 -> transpose+cast W (R10-proven); z>=4 -> cast X ----------------
__global__ __launch_bounds__(256) void prep_kernel(const float* __restrict__ X,
                                                   const float* __restrict__ W0,
                                                   const float* __restrict__ W1,
                                                   const float* __restrict__ W2,
                                                   const float* __restrict__ W3,
                                                   unsigned short* __restrict__ Xbf,
                                                   unsigned short* __restrict__ D0,
                                                   unsigned short* __restrict__ D1,
                                                   unsigned short* __restrict__ D2,
                                                   unsigned short* __restrict__ D3) {
  int z = blockIdx.z;
  if (z >= 4) {  // cast 4096x1024 fp32 -> bf16; z in {4,5}
    long bid = (long)(z - 4) * 1024 + blockIdx.y * 32 + blockIdx.x;
    int tl = threadIdx.y * 32 + threadIdx.x;
    long i = bid * 2048 + (long)tl * 8;
    float4 f0 = *(const float4*)(X + i);
    float4 f1 = *(const float4*)(X + i + 4);
    ushortx8 u;
    u[0] = f2bf(f0.x); u[1] = f2bf(f0.y); u[2] = f2bf(f0.z); u[3] = f2bf(f0.w);
    u[4] = f2bf(f1.x); u[5] = f2bf(f1.y); u[6] = f2bf(f1.z); u[7] = f2bf(f1.w);
    *(ushortx8*)(Xbf + i) = u;
    return;
  }
  const float* src = (z == 0) ? W0 : (z == 1) ? W1 : (z == 2) ? W2 : W3;
  unsigned short* dst = (z == 0) ? D0 : (z == 1) ? D1 : (z == 2) ? D2 : D3;
  const int R = 1024, C = 1024;
  __shared__ unsigned short t[32][33];
  int c = blockIdx.x * 32 + threadIdx.x;
#pragma unroll
  for (int i = 0; i < 4; ++i) {
    int r = blockIdx.y * 32 + threadIdx.y + i * 8;
    t[threadIdx.y + i * 8][threadIdx.x] = f2bf(src[(size_t)r * C + c]);
  }
  __syncthreads();
  int rr = blockIdx.y * 32 + threadIdx.x;
#pragma unroll
  for (int i = 0; i < 4; ++i) {
    int cc = blockIdx.x * 32 + threadIdx.y + i * 8;
    dst[(size_t)cc * R + rr] = t[threadIdx.x][threadIdx.y + i * 8];
  }
}

// ---------------- QKV GEMM: 128x128 tile, BK=32, static-dbuf async prefetch ----
// Swizzle: R10-measured variant (fs = c4 ^ (r4&3)); the "conflict-free" ((r4>>1)&3)
// variant measured SLOWER (63 vs 51 us) despite SQ_LDS_BANK_CONFLICT 3.1M->0 — the
// conflicts are hidden under MFMA+TLP; keep the faster-measured mapping.
__global__ __launch_bounds__(256) void gemm128_kernel(
    const unsigned short* __restrict__ A,
    const unsigned short* __restrict__ BT0,
    const unsigned short* __restrict__ BT1,
    const unsigned short* __restrict__ BT2,
    unsigned short* __restrict__ outQ,
    unsigned short* __restrict__ outK,
    unsigned short* __restrict__ outVT,
    const int* __restrict__ pos_ids,
    const float* __restrict__ cosb,
    const float* __restrict__ sinb) {
  const int K = 1024;
  int id = blockIdx.x + 8 * (blockIdx.y + 32 * blockIdx.z);
  int m_idx = id & 31;         // m fastest => xcd = id%8 = m_idx%8
  int nzi = id >> 5;
  int n_idx = nzi & 7;
  int z = nzi >> 3;
  const unsigned short* BT = (z == 0) ? BT0 : (z == 1 ? BT1 : BT2);
  int n0 = n_idx * 128, m0 = m_idx * 128;
  int t = threadIdx.x, lane = t & 63, w = t >> 6;
  int wy = w >> 1, wx = w & 1;
  int n16 = lane & 15, quad = lane >> 4;
  __shared__ __align__(16) unsigned short sA0[128 * 32];
  __shared__ __align__(16) unsigned short sA1[128 * 32];
  __shared__ __align__(16) unsigned short sB0[128 * 32];
  __shared__ __align__(16) unsigned short sB1[128 * 32];

  int r4 = lane >> 2, c4 = lane & 3;
  int fs = c4 ^ (r4 & 3);  // R10 mapping: slot c4 of rows r4, r4+16 holds chunk fs
  const char* gA = (const char*)(A + (size_t)(m0 + w * 32 + r4) * K) + fs * 16;
  const char* gB = (const char*)(BT + (size_t)(n0 + w * 32 + r4) * K) + fs * 16;
  const size_t row16 = (size_t)16 * K * 2;

  f32x4 acc[4][4];
#pragma unroll
  for (int i = 0; i < 4; ++i)
#pragma unroll
    for (int j = 0; j < 4; ++j) acc[i][j] = f32x4{0.f, 0.f, 0.f, 0.f};

#define GSTAGE(kk_, SA, SB)                                                     \
  do {                                                                          \
    GLL16(gA + (size_t)(kk_) * 2, SA + (w * 32) * 32);                          \
    GLL16(gA + (size_t)(kk_) * 2 + row16, SA + (w * 32 + 16) * 32);             \
    GLL16(gB + (size_t)(kk_) * 2, SB + (w * 32) * 32);                          \
    GLL16(gB + (size_t)(kk_) * 2 + row16, SB + (w * 32 + 16) * 32);             \
  } while (0)

#define GCOMPUTE(SA, SB)                                                        \
  do {                                                                          \
    bf16x8 a[4], b[4];                                                          \
    int cs = (quad ^ (n16 & 3)) * 8;                                            \
    _Pragma("unroll") for (int i = 0; i < 4; ++i) {                             \
      a[i] = *(const bf16x8*)(&SA[(wy * 64 + i * 16 + n16) * 32 + cs]);         \
      b[i] = *(const bf16x8*)(&SB[(wx * 64 + i * 16 + n16) * 32 + cs]);         \
    }                                                                           \
    _Pragma("unroll") for (int mt = 0; mt < 4; ++mt)                            \
      _Pragma("unroll") for (int nt = 0; nt < 4; ++nt)                          \
        acc[mt][nt] = __builtin_amdgcn_mfma_f32_16x16x32_bf16(                  \
            a[mt], b[nt], acc[mt][nt], 0, 0, 0);                                \
  } while (0)

  GSTAGE(0, sA0, sB0);
  for (int kk = 0; kk < K;) {
    __syncthreads();
    if (kk + 32 < K) GSTAGE(kk + 32, sA1, sB1);
    GCOMPUTE(sA0, sB0);
    kk += 32;
    if (kk >= K) break;
    __syncthreads();
    if (kk + 32 < K) GSTAGE(kk + 32, sA0, sB0);
    GCOMPUTE(sA1, sB1);
    kk += 32;
  }
#undef GSTAGE
#undef GCOMPUTE

  if (z < 2) {  // fused RoPE on Q/K; Q additionally pre-scaled by SCALE*log2(e)
    const float qs = (z == 0) ? (0.125f * 1.44269504088896340736f) : 1.0f;
#pragma unroll
    for (int mt = 0; mt < 4; ++mt)
#pragma unroll
      for (int r = 0; r < 4; ++r) {
        int row = m0 + wy * 64 + mt * 16 + quad * 4 + r;
        int b = row >> 11, s = row & 2047;
        int pos = pos_ids[b * 2048 + s];
        const float* cb = cosb + (size_t)pos * 64;
        const float* sb = sinb + (size_t)pos * 64;
#pragma unroll
        for (int nt = 0; nt < 2; ++nt) {
          int d0 = nt * 16 + n16;
          float c0 = cb[d0] * qs, s0 = sb[d0] * qs;
          float c1 = cb[d0 + 32] * qs, s1 = sb[d0 + 32] * qs;
          float x0 = acc[mt][nt][r], x1 = acc[mt][nt + 2][r];
          acc[mt][nt][r]     = x0 * c0 - x1 * s0;
          acc[mt][nt + 2][r] = x1 * c1 + x0 * s1;
        }
      }
  }

  if (z == 2) {
    // V^T fused write: VT[((b*16+h)*64+d)*2048 + s]
#pragma unroll
    for (int mt = 0; mt < 4; ++mt)
#pragma unroll
      for (int nt = 0; nt < 4; ++nt) {
        int row = m0 + wy * 64 + mt * 16 + quad * 4;
        int b = row >> 11, s = row & 2047;
        int col = n0 + wx * 64 + nt * 16 + n16;
        int h = col >> 6, d = col & 63;
        ushortx4 u;
#pragma unroll
        for (int r = 0; r < 4; ++r) u[r] = f2bf(acc[mt][nt][r]);
        *(ushortx4*)(&outVT[(((size_t)b * 16 + h) * 64 + d) * 2048 + s]) = u;
      }
    return;
  }

#pragma unroll
  for (int mt = 0; mt < 4; ++mt)
#pragma unroll
    for (int nt = 0; nt < 4; ++nt)
#pragma unroll
      for (int r = 0; r < 4; ++r) {
        int row = m0 + wy * 64 + mt * 16 + quad * 4 + r;
        int col = n0 + wx * 64 + nt * 16 + n16;
        unsigned short* dst = (z == 0) ? outQ : outK;
        int b = row >> 11, s = row & 2047, h = col >> 6, d = col & 63;
        dst[(((size_t)b * 16 + h) * 2048 + s) * 64 + d] = f2bf(acc[mt][nt][r]);
      }
}

// ---------------- Wo GEMM: 64x64 tile -> 1024 blocks (4/CU), BK=32 static-dbuf ----
__global__ __launch_bounds__(256) void gemm64_kernel(const unsigned short* __restrict__ A,
                                                     const unsigned short* __restrict__ BT,
                                                     float* __restrict__ outF) {
  const int K = 1024, N = 1024;
  int m0 = blockIdx.x * 64, n0 = blockIdx.y * 64;
  int t = threadIdx.x, lane = t & 63, w = t >> 6;
  int wy = w >> 1, wx = w & 1;
  int n16 = lane & 15, quad = lane >> 4;
  __shared__ __align__(16) unsigned short sA0[64 * 32];
  __shared__ __align__(16) unsigned short sA1[64 * 32];
  __shared__ __align__(16) unsigned short sB0[64 * 32];
  __shared__ __align__(16) unsigned short sB1[64 * 32];

  int r4 = lane >> 2, c4 = lane & 3;
  int fs = c4 ^ (r4 & 3);  // R10 mapping
  const char* gA = (const char*)(A + (size_t)(m0 + w * 16 + r4) * K) + fs * 16;
  const char* gB = (const char*)(BT + (size_t)(n0 + w * 16 + r4) * K) + fs * 16;

  f32x4 acc[2][2];
#pragma unroll
  for (int i = 0; i < 2; ++i)
#pragma unroll
    for (int j = 0; j < 2; ++j) acc[i][j] = f32x4{0.f, 0.f, 0.f, 0.f};

#define WSTAGE(kk_, SA, SB)                                                     \
  do {                                                                          \
    GLL16(gA + (size_t)(kk_) * 2, SA + (w * 16) * 32);                          \
    GLL16(gB + (size_t)(kk_) * 2, SB + (w * 16) * 32);                          \
  } while (0)

#define WCOMPUTE(SA, SB)                                                        \
  do {                                                                          \
    int cs = (quad ^ (n16 & 3)) * 8;                                            \
    bf16x8 a0 = *(const bf16x8*)(&SA[(wy * 32 + n16) * 32 + cs]);               \
    bf16x8 a1 = *(const bf16x8*)(&SA[(wy * 32 + 16 + n16) * 32 + cs]);          \
    bf16x8 b0 = *(const bf16x8*)(&SB[(wx * 32 + n16) * 32 + cs]);               \
    bf16x8 b1 = *(const bf16x8*)(&SB[(wx * 32 + 16 + n16) * 32 + cs]);          \
    acc[0][0] = __builtin_amdgcn_mfma_f32_16x16x32_bf16(a0, b0, acc[0][0], 0, 0, 0); \
    acc[0][1] = __builtin_amdgcn_mfma_f32_16x16x32_bf16(a0, b1, acc[0][1], 0, 0, 0); \
    acc[1][0] = __builtin_amdgcn_mfma_f32_16x16x32_bf16(a1, b0, acc[1][0], 0, 0, 0); \
    acc[1][1] = __builtin_amdgcn_mfma_f32_16x16x32_bf16(a1, b1, acc[1][1], 0, 0, 0); \
  } while (0)

  WSTAGE(0, sA0, sB0);
  for (int kk = 0; kk < K;) {
    __syncthreads();
    if (kk + 32 < K) WSTAGE(kk + 32, sA1, sB1);
    WCOMPUTE(sA0, sB0);
    kk += 32;
    if (kk >= K) break;
    __syncthreads();
    if (kk + 32 < K) WSTAGE(kk + 32, sA0, sB0);
    WCOMPUTE(sA1, sB1);
    kk += 32;
  }
#undef WSTAGE
#undef WCOMPUTE

#pragma unroll
  for (int mt = 0; mt < 2; ++mt)
#pragma unroll
    for (int nt = 0; nt < 2; ++nt)
#pragma unroll
      for (int r = 0; r < 4; ++r) {
        int row = m0 + wy * 32 + mt * 16 + quad * 4 + r;
        int col = n0 + wx * 32 + nt * 16 + n16;
        outF[(size_t)row * N + col] = acc[mt][nt][r];
      }
}

// ---------------- Flash attention v8: q-tile 128, K-tile 128, 8 waves, dbuf ----
// S^T orientation; lane owns q-row qg. One softmax round + one barrier per 128 k-cols.
// PV done in two 64-k halves so sP stays 16x64/wave (80 KB total LDS -> 2 blk/CU).
__global__ __launch_bounds__(512, 4) void attn_kernel(const unsigned short* __restrict__ Q,
                                                      const unsigned short* __restrict__ Kk,
                                                      const unsigned short* __restrict__ VT,
                                                      unsigned short* __restrict__ O) {
  int bh = blockIdx.x;
  int qt = (int)(gridDim.y - 1 - blockIdx.y);  // 0..15, LPT
  int t = threadIdx.x;
  int lane = t & 63;
  int w = t >> 6;  // 0..7
  int n16 = lane & 15, quad = lane >> 4;
  int r8 = lane >> 3, c8 = lane & 7;   // K staging coords
  int rv = lane >> 4, cv = lane & 15;  // V staging coords
  const unsigned short* Qb = Q + (size_t)bh * 2048 * 64;
  const unsigned short* Kb = Kk + (size_t)bh * 2048 * 64;
  const unsigned short* Vb = VT + (size_t)bh * 64 * 2048;

  __shared__ __align__(16) unsigned short sK0[128 * 64];
  __shared__ __align__(16) unsigned short sK1[128 * 64];
  __shared__ __align__(16) unsigned short sV0[64 * 128];
  __shared__ __align__(16) unsigned short sV1[64 * 128];
  __shared__ __align__(16) unsigned short sP[8][16 * 64];
  unsigned short* spW = sP[w];

  int b_ = bh >> 4, h_ = bh & 15;
  int nk = qt + 1;
  int qg = qt * 128 + w * 16 + n16;  // this lane's q-row

  bf16x8 aQ[2];
#pragma unroll
  for (int kb = 0; kb < 2; ++kb)
    aQ[kb] = *(const bf16x8*)(Qb + (size_t)qg * 64 + kb * 32 + quad * 8);

  f32x4 o[4];
  float mst = -3e38f, lst = 0.f;
#pragma unroll
  for (int ct = 0; ct < 4; ++ct) o[ct] = f32x4{0.f, 0.f, 0.f, 0.f};

#define ASTAGE(kt_, SK, SV)                                                               \
  do {                                                                                    \
    const unsigned short* kg_ = Kb + (size_t)((kt_) * 128 + w * 16) * 64;                 \
    const unsigned short* vg_ = Vb + (size_t)(w * 8) * 2048 + (kt_) * 128;                \
    GLL16(kg_ + (size_t)r8 * 64 + (c8 ^ r8) * 8, SK + (w * 16) * 64);                     \
    GLL16(kg_ + (size_t)(8 + r8) * 64 + (c8 ^ r8) * 8, SK + (w * 16 + 8) * 64);           \
    GLL16(vg_ + (size_t)rv * 2048 + (cv ^ rv) * 8, SV + (w * 8) * 128);                   \
    GLL16(vg_ + (size_t)(4 + rv) * 2048 + (cv ^ (4 + rv)) * 8, SV + (w * 8 + 4) * 128);   \
  } while (0)

#define ACOMPUTE(kt_, SK, SV)                                                             \
  do {                                                                                    \
    f32x4 ps[2][4]; /* S^T: D[m=k][n=q]; 2 halves x 4 mt */                               \
    _Pragma("unroll") for (int h = 0; h < 2; ++h)                                         \
      _Pragma("unroll") for (int mt = 0; mt < 4; ++mt) {                                  \
        const unsigned short* kr = &SK[(h * 64 + mt * 16 + n16) * 64];                    \
        bf16x8 ka0 = *(const bf16x8*)(kr + ((quad ^ (n16 & 7)) * 8));                     \
        bf16x8 ka1 = *(const bf16x8*)(kr + (((4 + quad) ^ (n16 & 7)) * 8));               \
        f32x4 zv = f32x4{0.f, 0.f, 0.f, 0.f};                                             \
        zv = __builtin_amdgcn_mfma_f32_16x16x32_bf16(ka0, aQ[0], zv, 0, 0, 0);            \
        ps[h][mt] = __builtin_amdgcn_mfma_f32_16x16x32_bf16(ka1, aQ[1], zv, 0, 0, 0);     \
      }                                                                                   \
    if ((kt_) == nk - 1) { /* diagonal: mask k > q */                                     \
      _Pragma("unroll") for (int h = 0; h < 2; ++h)                                       \
        _Pragma("unroll") for (int mt = 0; mt < 4; ++mt)                                  \
          _Pragma("unroll") for (int r = 0; r < 4; ++r)                                   \
            if ((kt_) * 128 + h * 64 + mt * 16 + quad * 4 + r > qg) ps[h][mt][r] = -3e38f;\
    }                                                                                     \
    float rm = ps[0][0][0];                                                               \
    _Pragma("unroll") for (int h = 0; h < 2; ++h)                                         \
      _Pragma("unroll") for (int mt = 0; mt < 4; ++mt)                                    \
        _Pragma("unroll") for (int r = 0; r < 4; ++r) rm = fmaxf(rm, ps[h][mt][r]);       \
    rm = fmaxf(rm, __shfl_xor(rm, 16));                                                   \
    rm = fmaxf(rm, __shfl_xor(rm, 32));                                                   \
    float mn = fmaxf(mst, rm);                                                            \
    float al = exp2f(mst - mn);                                                           \
    mst = mn;                                                                             \
    float rs = 0.f;                                                                       \
    _Pragma("unroll") for (int h = 0; h < 2; ++h)                                         \
      _Pragma("unroll") for (int mt = 0; mt < 4; ++mt)                                    \
        _Pragma("unroll") for (int r = 0; r < 4; ++r) {                                   \
          ps[h][mt][r] = exp2f(ps[h][mt][r] - mn);                                        \
          rs += ps[h][mt][r];                                                             \
        }                                                                                 \
    lst = lst * al + rs;                                                                  \
    _Pragma("unroll") for (int ct = 0; ct < 4; ++ct)                                      \
      _Pragma("unroll") for (int r = 0; r < 4; ++r) o[ct][r] *= al;                       \
    _Pragma("unroll") for (int h = 0; h < 2; ++h) {                                       \
      _Pragma("unroll") for (int mt = 0; mt < 4; ++mt) {                                  \
        ushortx4 uu;                                                                      \
        _Pragma("unroll") for (int r = 0; r < 4; ++r) uu[r] = f2bf_fast(ps[h][mt][r]);    \
        int ch = (2 * mt + (quad >> 1)) ^ (n16 & 7);                                      \
        *(ushortx4*)(&spW[n16 * 64 + ch * 8 + (quad & 1) * 4]) = uu;                      \
      }                                                                                   \
      __builtin_amdgcn_s_waitcnt(0xC07F); /* lgkmcnt(0); GLL prefetch stays in flight */  \
      bf16x8 aP0 = *(const bf16x8*)(&spW[n16 * 64 + ((quad ^ (n16 & 7)) * 8)]);           \
      bf16x8 aP1 = *(const bf16x8*)(&spW[n16 * 64 + (((4 + quad) ^ (n16 & 7)) * 8)]);     \
      _Pragma("unroll") for (int ct = 0; ct < 4; ++ct) {                                  \
        const unsigned short* vr = &SV[(ct * 16 + n16) * 128];                            \
        bf16x8 va0 = *(const bf16x8*)(vr + ((((h * 2 + 0) * 4 + quad) ^ (n16 & 7)) * 8)); \
        bf16x8 va1 = *(const bf16x8*)(vr + ((((h * 2 + 1) * 4 + quad) ^ (n16 & 7)) * 8)); \
        o[ct] = __builtin_amdgcn_mfma_f32_16x16x32_bf16(va0, aP0, o[ct], 0, 0, 0);        \
        o[ct] = __builtin_amdgcn_mfma_f32_16x16x32_bf16(va1, aP1, o[ct], 0, 0, 0);        \
      }                                                                                   \
    }                                                                                     \
  } while (0)

  ASTAGE(0, sK0, sV0);
  int kt = 0;
  while (true) {
    __syncthreads();  // drains loads into sK0/sV0
    if (kt + 1 < nk) ASTAGE(kt + 1, sK1, sV1);
    ACOMPUTE(kt, sK0, sV0);
    if (++kt == nk) break;
    __syncthreads();  // drains loads into sK1/sV1
    if (kt + 1 < nk) ASTAGE(kt + 1, sK0, sV0);
    ACOMPUTE(kt, sK1, sV1);
    if (++kt == nk) break;
  }
#undef ASTAGE
#undef ACOMPUTE

  // cross-quad l reduction (quads hold disjoint k-partials)
  lst += __shfl_xor(lst, 16);
  lst += __shfl_xor(lst, 32);
  float inv = 1.0f / lst;

#pragma unroll
  for (int ct = 0; ct < 4; ++ct) {
    ushortx4 uo;
#pragma unroll
    for (int r = 0; r < 4; ++r) uo[r] = f2bf(o[ct][r] * inv);
    size_t addr = ((size_t)b_ * 2048 + qg) * 1024 + h_ * 64 + ct * 16 + quad * 4;
    *(ushortx4*)(&O[addr]) = uo;
  }
}

// ---------------- launch ----------------
extern "C" void kernel_launch(void* const* d_in, const int* in_sizes, int n_in,
                              void* d_out, int out_size, void* d_ws, size_t ws_size,
                              hipStream_t stream) {
  const float* X    = (const float*)d_in[0];
  const int*   pos  = (const int*)d_in[2];
  const float* cosb = (const float*)d_in[3];
  const float* sinb = (const float*)d_in[4];
  const float* Wq   = (const float*)d_in[5];
  const float* Wk   = (const float*)d_in[6];
  const float* Wv   = (const float*)d_in[7];
  const float* Wo   = (const float*)d_in[8];
  float* out = (float*)d_out;

  char* ws = (char*)d_ws;
  const size_t SZ_X = 4096UL * 1024 * 2;
  const size_t SZ_W = 1024UL * 1024 * 2;
  unsigned short* Xbf = (unsigned short*)(ws);
  unsigned short* WTq = (unsigned short*)(ws + SZ_X);
  unsigned short* WTk = (unsigned short*)(ws + SZ_X + SZ_W);
  unsigned short* WTv = (unsigned short*)(ws + SZ_X + 2 * SZ_W);
  unsigned short* WTo = (unsigned short*)(ws + SZ_X + 3 * SZ_W);
  unsigned short* Qbf = (unsigned short*)(ws + SZ_X + 4 * SZ_W);
  unsigned short* Kbf = (unsigned short*)(ws + 2 * SZ_X + 4 * SZ_W);
  unsigned short* VTr = (unsigned short*)(ws + 3 * SZ_X + 4 * SZ_W);
  unsigned short* Obf = (unsigned short*)(ws + 4 * SZ_X + 4 * SZ_W);

  prep_kernel<<<dim3(32, 32, 6), dim3(32, 8), 0, stream>>>(
      X, Wq, Wk, Wv, Wo, Xbf, WTq, WTk, WTv, WTo);

  // QKV projections + fused RoPE (Q pre-scaled) + fused V-transpose
  gemm128_kernel<<<dim3(8, 32, 3), 256, 0, stream>>>(Xbf, WTq, WTk, WTv,
                                                     Qbf, Kbf, VTr,
                                                     pos, cosb, sinb);

  attn_kernel<<<dim3(32, 16), 512, 0, stream>>>(Qbf, Kbf, VTr, Obf);

  gemm64_kernel<<<dim3(64, 16), 256, 0, stream>>>(Obf, WTo, out);
}